// Round 6
// baseline (53.559 us; speedup 1.0000x reference)
//
#include <hip/hip_runtime.h>
#include <math.h>

#define RG 61
#define CG 61
#define NP 3721           // RG*CG
#define NSEG 3722         // NP+1
#define NCLS 10
#define NPATCH 4          // patches per block
#define NCG 16            // column groups (c0 = 4*g, last clamped to 57)
#define KS 2              // K slices (window rows 0..31 / 32..63)
#define NBLK (RG*NCG*KS)  // 1952
#define ROWS_SLICE 32
#define ITERS 12          // 32 rows * 96 pairs / 256 threads
#define IMGF 336          // floats per staged row: 112 px * 3
#define LDSF (ROWS_SLICE*IMGF)   // 10752 floats = 43008 B
#define THRESHV 0.7f
#define BIGI 0x3FFFFFFF

#define SBAR() __builtin_amdgcn_sched_barrier(0)

// ---------------------------------------------------------------------------
// Kernel 1: partial logits. Block = (r, cgroup, ks). Stage the 32-row x 112-px
// img slice into LDS once (one HBM latency per block, not one per iter), then
// inner loop: x from LDS (contiguous b64, conflict-free), W from global
// (491KB shared by all blocks -> L2-hit, covered by 2-deep A/B pipeline).
// XCD-swizzled blockIdx: same-r blocks share img rows in one XCD's L2.
// ---------------------------------------------------------------------------
#define DECLBUF(S) float4 wa##S, wb##S, wc##S, wd##S, we##S; \
                   float2 x0##S, x1##S, x2##S, x3##S;

#define LOADAB(S, IT) { \
    const int pi_  = (IT) * 256 + tid; \
    const int il_  = pi_ / 96;               /* local window-row  */ \
    const int rem_ = (pi_ - il_ * 96) * 2;   /* even, 0..190      */ \
    const float* wp_ = W + (size_t)((ks * ROWS_SLICE + il_) * 192 + rem_) * NCLS; \
    wa##S = *(const float4*)(wp_); \
    wb##S = *(const float4*)(wp_ + 4); \
    wc##S = *(const float4*)(wp_ + 8); \
    wd##S = *(const float4*)(wp_ + 12); \
    we##S = *(const float4*)(wp_ + 16); \
    const float* xb_ = s + il_ * IMGF + rem_; \
    x0##S = *(const float2*)(xb_); \
    x1##S = *(const float2*)(xb_ + 48); \
    x2##S = *(const float2*)(xb_ + 96); \
    x3##S = *(const float2*)(xb_ + 144); \
}

#define FMAS(S) { \
    const float w0_[NCLS] = {wa##S.x, wa##S.y, wa##S.z, wa##S.w, \
                             wb##S.x, wb##S.y, wb##S.z, wb##S.w, wc##S.x, wc##S.y}; \
    const float w1_[NCLS] = {wc##S.z, wc##S.w, wd##S.x, wd##S.y, \
                             wd##S.z, wd##S.w, we##S.x, we##S.y, we##S.z, we##S.w}; \
    const float2 xs_[NPATCH] = {x0##S, x1##S, x2##S, x3##S}; \
    _Pragma("unroll") \
    for (int p_ = 0; p_ < NPATCH; ++p_) { \
        _Pragma("unroll") \
        for (int k_ = 0; k_ < NCLS; ++k_) { \
            acc[p_][k_] = fmaf(xs_[p_].x, w0_[k_], acc[p_][k_]); \
            acc[p_][k_] = fmaf(xs_[p_].y, w1_[k_], acc[p_][k_]); \
        } \
    } \
}

__global__ __launch_bounds__(256, 3) void wod_logits_part(
    const float* __restrict__ img,   // (1024,1024,3)
    const float* __restrict__ W,     // (12288,10)
    float* __restrict__ part)        // (NBLK, 40)
{
    __shared__ float s[LDSF];
    const int tid = threadIdx.x;
    // bijective XCD swizzle (1952 = 8*244): consecutive o -> same XCD
    const int o  = (blockIdx.x & 7) * 244 + (blockIdx.x >> 3);
    const int r  = o >> 5;             // 0..60
    const int gg = (o >> 1) & 15;      // column group
    const int ks = o & 1;              // K slice
    const int c0 = (gg < 15) ? gg * 4 : 57;   // clamp: 4 patches always valid
    const int R0 = 16 * r + ROWS_SLICE * ks;  // first image row of slice

    // ---- stage img slice: 32 rows x 336 floats (2688 float4), coalesced ----
    const float* gsrc = img + (size_t)R0 * 3072 + c0 * 48;
    for (int u = tid; u < (LDSF >> 2); u += 256) {
        const int row  = u / 84;
        const int col4 = u - row * 84;
        const float4 v = *(const float4*)(gsrc + row * 3072 + col4 * 4);
        *(float4*)(s + row * IMGF + col4 * 4) = v;
    }
    __syncthreads();

    float acc[NPATCH][NCLS];
    #pragma unroll
    for (int p = 0; p < NPATCH; ++p)
        #pragma unroll
        for (int k = 0; k < NCLS; ++k) acc[p][k] = 0.f;

    DECLBUF(A)
    DECLBUF(B)

    LOADAB(A, 0)
    #pragma unroll 1
    for (int t = 0; t < ITERS / 2; ++t) {
        SBAR();
        LOADAB(B, 2 * t + 1)     // issue next-iter loads (W global + x LDS)
        SBAR();
        FMAS(A)                  // 160 FMA issue-cycles cover their latency
        SBAR();
        if (t < ITERS / 2 - 1) { LOADAB(A, 2 * t + 2) }
        SBAR();
        FMAS(B)
        SBAR();
    }

    // ---- block reduction of 40 partials over 256 threads ----
    #pragma unroll
    for (int p = 0; p < NPATCH; ++p)
        #pragma unroll
        for (int k = 0; k < NCLS; ++k) {
            float v = acc[p][k];
            v += __shfl_down(v, 1);
            v += __shfl_down(v, 2);
            v += __shfl_down(v, 4);
            acc[p][k] = v;
        }

    __syncthreads();   // all img reads done; reuse s[] as reduction scratch
    const int lane = tid & 63, wave = tid >> 6;
    if ((lane & 7) == 0) {
        const int row = wave * 8 + (lane >> 3);
        #pragma unroll
        for (int p = 0; p < NPATCH; ++p)
            #pragma unroll
            for (int k = 0; k < NCLS; ++k)
                s[row * 40 + p * NCLS + k] = acc[p][k];
    }
    __syncthreads();
    if (tid < NPATCH * NCLS) {
        float sum = 0.f;
        #pragma unroll
        for (int j = 0; j < 32; ++j) sum += s[j * 40 + tid];
        part[o * (NPATCH * NCLS) + tid] = sum;
    }
}

// ---------------------------------------------------------------------------
// Kernel 2: reduce KS partials + bias + softmax + prob + mask.
// ---------------------------------------------------------------------------
__global__ __launch_bounds__(256) void wod_reduce(
    const float* __restrict__ part,   // (NBLK, 40)
    const float* __restrict__ bias,   // (10)
    float* __restrict__ out_prob,     // (61,61,10)
    int* __restrict__ mask)           // (10,3721)
{
    const int cell = blockIdx.x * 256 + threadIdx.x;
    if (cell >= NP) return;
    const int r  = cell / CG;
    const int c  = cell - r * CG;
    int cg = c >> 2; if (cg > 15) cg = 15;
    const int c0 = (cg < 15) ? cg * 4 : 57;
    const int p  = c - c0;
    const int o0 = r * 32 + cg * 2;           // ks=0 block
    const int gb0 = o0 * (NPATCH * NCLS) + p * NCLS;
    const int gb1 = (o0 + 1) * (NPATCH * NCLS) + p * NCLS;

    float lg[NCLS];
    #pragma unroll
    for (int k = 0; k < NCLS; ++k)
        lg[k] = bias[k] + part[gb0 + k] + part[gb1 + k];

    float m = -1e30f;
    #pragma unroll
    for (int k = 0; k < NCLS; ++k) m = fmaxf(m, lg[k]);
    float ex[NCLS], sm = 0.f;
    #pragma unroll
    for (int k = 0; k < NCLS; ++k) { ex[k] = expf(lg[k] - m); sm += ex[k]; }
    const float inv = 1.f / sm;
    const int base = cell * NCLS;
    #pragma unroll
    for (int k = 0; k < NCLS; ++k) {
        const float pr = ex[k] * inv;
        out_prob[base + k] = pr;
        mask[k * NP + cell] = (pr > THRESHV) ? 1 : 0;
    }
}

// ---------------------------------------------------------------------------
// Kernel 3: connected components (min-label propagation in LDS) + labels +
// boxes + valid, all fused. One block per class.
// ---------------------------------------------------------------------------
__global__ __launch_bounds__(256) void wod_cc(
    const int* __restrict__ mask,     // (10,3721)
    float* __restrict__ out_lbl,      // (61,61,10) as float
    float* __restrict__ out_box,      // (10,3722,4)
    float* __restrict__ out_valid)    // (10,3722)
{
    const int k = blockIdx.x;
    const int tid = threadIdx.x;
    __shared__ int lbl[NP];
    __shared__ int ext0[NSEG], ext1[NSEG];
    __shared__ int changed;

    const int* mk = mask + k * NP;
    for (int idx = tid; idx < NP; idx += 256)
        lbl[idx] = mk[idx] ? (idx + 1) : 0;
    if (tid == 0) changed = 0;
    __syncthreads();

    for (;;) {
        for (int idx = tid; idx < NP; idx += 256) {
            int v = lbl[idx];
            if (v) {
                const int rr = idx / CG;
                const int cc = idx - rr * CG;
                int best = v;
                if (rr > 0)      { int n = lbl[idx - CG]; if (n && n < best) best = n; }
                if (rr < RG - 1) { int n = lbl[idx + CG]; if (n && n < best) best = n; }
                if (cc > 0)      { int n = lbl[idx - 1];  if (n && n < best) best = n; }
                if (cc < CG - 1) { int n = lbl[idx + 1];  if (n && n < best) best = n; }
                if (best < v) { lbl[idx] = best; changed = 1; }
            }
        }
        __syncthreads();
        const bool stop = (changed == 0);
        __syncthreads();           // all reads of `changed` done before reset
        if (stop) break;
        if (tid == 0) changed = 0;
        __syncthreads();
    }

    // labels out (transposed to (r,c,k))
    for (int idx = tid; idx < NP; idx += 256)
        out_lbl[idx * NCLS + k] = (float)lbl[idx];

    float* boxk = out_box + k * NSEG * 4;
    float* valk = out_valid + k * NSEG;

    // pass 1: rmin / cmin
    for (int s2 = tid; s2 < NSEG; s2 += 256) { ext0[s2] = BIGI; ext1[s2] = BIGI; }
    __syncthreads();
    for (int idx = tid; idx < NP; idx += 256) {
        const int v = lbl[idx];
        if (v) {
            const int rr = idx / CG, cc = idx - rr * CG;
            atomicMin(&ext0[v], rr);
            atomicMin(&ext1[v], cc);
        }
    }
    __syncthreads();
    for (int s2 = tid; s2 < NSEG; s2 += 256) {
        const bool valid = (s2 > 0) && (ext0[s2] != BIGI);
        boxk[s2 * 4 + 0] = valid ? (float)(ext0[s2] - 1) : -1.f;
        boxk[s2 * 4 + 1] = valid ? (float)(ext1[s2] - 1) : -1.f;
        valk[s2] = valid ? 1.f : 0.f;
    }
    __syncthreads();

    // pass 2: rmax / cmax
    for (int s2 = tid; s2 < NSEG; s2 += 256) { ext0[s2] = -1; ext1[s2] = -1; }
    __syncthreads();
    for (int idx = tid; idx < NP; idx += 256) {
        const int v = lbl[idx];
        if (v) {
            const int rr = idx / CG, cc = idx - rr * CG;
            atomicMax(&ext0[v], rr);
            atomicMax(&ext1[v], cc);
        }
    }
    __syncthreads();
    for (int s2 = tid; s2 < NSEG; s2 += 256) {
        const bool valid = (s2 > 0) && (ext0[s2] >= 0);
        boxk[s2 * 4 + 2] = valid ? (float)(ext0[s2] + 1) : -1.f;
        boxk[s2 * 4 + 3] = valid ? (float)(ext1[s2] + 1) : -1.f;
    }
}

// ---------------------------------------------------------------------------
extern "C" void kernel_launch(void* const* d_in, const int* in_sizes, int n_in,
                              void* d_out, int out_size, void* d_ws, size_t ws_size,
                              hipStream_t stream) {
    (void)in_sizes; (void)n_in; (void)out_size; (void)ws_size;
    const float* img = (const float*)d_in[0];
    const float* W   = (const float*)d_in[1];
    const float* b   = (const float*)d_in[2];

    float* out       = (float*)d_out;
    float* out_prob  = out;                       // 37210
    float* out_lbl   = out + 37210;               // 37210
    float* out_box   = out + 74420;               // 148880
    float* out_valid = out + 223300;              // 37220

    int*   mask = (int*)d_ws;                     // 10*3721
    float* part = (float*)d_ws + NCLS * NP;       // NBLK*40 floats

    hipLaunchKernelGGL(wod_logits_part, dim3(NBLK), dim3(256), 0, stream,
                       img, W, part);
    hipLaunchKernelGGL(wod_reduce, dim3((NP + 255) / 256), dim3(256), 0, stream,
                       part, b, out_prob, mask);
    hipLaunchKernelGGL(wod_cc, dim3(NCLS), dim3(256), 0, stream,
                       mask, out_lbl, out_box, out_valid);
}